// Round 1
// baseline (1383.491 us; speedup 1.0000x reference)
//
#include <hip/hip_runtime.h>
#include <math.h>

// RCC (criss-cross) attention, fp32. B=8, C=192, CQK=64, H=W=128.
//
// Stages:
//   kproj : Q,K,V = conv1x1(x)                      -> ws
//   kch   : per (b,w) column scores e_h (diag mask) -> Mh,Sh per (b,h,w)
//   kcw   : per (b,h) row scores e_w                -> Mw,Sw per (b,h,w)
//   kow   : per (b,h): joint softmax (Mh,Sh,Mw,Sw) -> out_w  -> d_out (raw)
//   koh   : per (b,w): out_h; final = gamma*(out_h + d_out) + x  (in place)
//
// ws layout (floats): Q[8][64][128][128] @0, K @8388608, V[8][192][128][128]
// @16777216, Mh @41943040, Sh,Mw,Sw following (131072 each). Total ~162 MB.

#define B_   8
#define C_   192
#define CQK_ 64
#define H_   128
#define W_   128
#define HW_  (H_*W_)

// ---------------------------------------------------------------- projection
__global__ __launch_bounds__(256) void kproj(
    const float* __restrict__ x,
    const float* __restrict__ Wq, const float* __restrict__ bq,
    const float* __restrict__ Wk, const float* __restrict__ bk,
    const float* __restrict__ Wv, const float* __restrict__ bv,
    float* __restrict__ Q, float* __restrict__ K, float* __restrict__ V)
{
    __shared__ float xs[C_*64];              // 48 KB: x[:,tile of 64 positions]
    const int s   = blockIdx.x;              // 2048 tiles
    const int n0  = s << 6;
    const int b   = n0 >> 14;
    const int hw0 = n0 & (HW_-1);
    const float* xb = x + (size_t)b*C_*HW_ + hw0;
    const int t = threadIdx.x;
    for (int i = t; i < C_*64; i += 256) {   // coalesced 256B rows
        const int c = i >> 6, ww = i & 63;
        xs[i] = xb[c*HW_ + ww];
    }
    __syncthreads();
    const int w  = t & 63;
    const int og = t >> 6;                   // wave id 0..3 -> 80 outputs each
    for (int ob = 0; ob < 10; ++ob) {
        // o0 wave-uniform -> W reads become scalar loads (SMEM pipe)
        const int o0 = __builtin_amdgcn_readfirstlane(og*80 + ob*8);
        const float *wb, *bb; float* out; int oo, nch;
        if (o0 < 64)       { wb = Wq; bb = bq; out = Q; oo = o0;       nch = CQK_; }
        else if (o0 < 128) { wb = Wk; bb = bk; out = K; oo = o0 - 64;  nch = CQK_; }
        else               { wb = Wv; bb = bv; out = V; oo = o0 - 128; nch = C_;   }
        const float* wr = wb + oo*C_;
        float acc[8];
        #pragma unroll
        for (int j = 0; j < 8; ++j) acc[j] = bb[oo+j];
        for (int c = 0; c < C_; ++c) {
            const float xv = xs[(c<<6) + w];
            #pragma unroll
            for (int j = 0; j < 8; ++j) acc[j] += wr[j*C_ + c] * xv;
        }
        float* op = out + ((size_t)b*nch + oo)*HW_ + hw0 + w;
        #pragma unroll
        for (int j = 0; j < 8; ++j) op[(size_t)j*HW_] = acc[j];
    }
}

// --------------------------------------------- column scores -> Mh,Sh (b,h,w)
__global__ __launch_bounds__(256) void kch(
    const float* __restrict__ Q, const float* __restrict__ K,
    float* __restrict__ Mh, float* __restrict__ Sh)
{
    __shared__ float Qc[CQK_*H_];            // [c][h], 32 KB
    __shared__ float Kc[CQK_*H_];
    const int bid = blockIdx.x;
    const int b = bid & 7, w = bid >> 3;     // b = XCD: w-siblings share L2 lines
    const float* Qb = Q + (size_t)b*CQK_*HW_ + w;
    const float* Kb = K + (size_t)b*CQK_*HW_ + w;
    const int t = threadIdx.x;
    for (int i = t; i < CQK_*H_; i += 256) { // strided column gather (L2-amortized)
        const int c = i >> 7, hh = i & 127;
        Qc[i] = Qb[c*HW_ + hh*W_];
        Kc[i] = Kb[c*HW_ + hh*W_];
    }
    __syncthreads();
    const int h = t >> 1, gh = t & 1, g0 = gh << 6;
    float e[64];
    #pragma unroll
    for (int j = 0; j < 64; ++j) e[j] = 0.f;
    for (int c = 0; c < CQK_; ++c) {
        const float qv = Qc[(c<<7) + h];
        #pragma unroll
        for (int j = 0; j < 64; ++j) e[j] += qv * Kc[(c<<7) + g0 + j];
    }
    #pragma unroll
    for (int j = 0; j < 64; ++j) if (g0 + j == h) e[j] = -INFINITY;  // diag mask
    float m = -INFINITY;
    #pragma unroll
    for (int j = 0; j < 64; ++j) m = fmaxf(m, e[j]);
    m = fmaxf(m, __shfl_xor(m, 1));
    float ss = 0.f;
    #pragma unroll
    for (int j = 0; j < 64; ++j) ss += __expf(e[j] - m);
    ss += __shfl_xor(ss, 1);
    if (gh == 0) {
        const int idx = (b*H_ + h)*W_ + w;
        Mh[idx] = m; Sh[idx] = ss;
    }
}

// ------------------------------------------------ row scores -> Mw,Sw (b,h,w)
__global__ __launch_bounds__(256) void kcw(
    const float* __restrict__ Q, const float* __restrict__ K,
    float* __restrict__ Mw, float* __restrict__ Sw)
{
    __shared__ float Qr[CQK_*W_];
    __shared__ float Kr[CQK_*W_];
    const int bid = blockIdx.x;
    const int b = bid >> 7, h = bid & 127;
    const float* Qb = Q + (size_t)b*CQK_*HW_ + h*W_;
    const float* Kb = K + (size_t)b*CQK_*HW_ + h*W_;
    const int t = threadIdx.x;
    for (int i = t; i < CQK_*W_; i += 256) { // coalesced rows
        Qr[i] = Qb[(i >> 7)*HW_ + (i & 127)];
        Kr[i] = Kb[(i >> 7)*HW_ + (i & 127)];
    }
    __syncthreads();
    const int w = t >> 1, vh = t & 1, v0 = vh << 6;
    float e[64];
    #pragma unroll
    for (int j = 0; j < 64; ++j) e[j] = 0.f;
    for (int c = 0; c < CQK_; ++c) {
        const float qv = Qr[(c<<7) + w];
        #pragma unroll
        for (int j = 0; j < 64; ++j) e[j] += qv * Kr[(c<<7) + v0 + j];
    }
    float m = -INFINITY;
    #pragma unroll
    for (int j = 0; j < 64; ++j) m = fmaxf(m, e[j]);
    m = fmaxf(m, __shfl_xor(m, 1));
    float ss = 0.f;
    #pragma unroll
    for (int j = 0; j < 64; ++j) ss += __expf(e[j] - m);
    ss += __shfl_xor(ss, 1);
    if (vh == 0) {
        const int idx = (b*H_ + h)*W_ + w;
        Mw[idx] = m; Sw[idx] = ss;
    }
}

// ---------------- row attention output: d_out = raw out_w (natural layout)
__global__ __launch_bounds__(256) void kow(
    const float* __restrict__ Q, const float* __restrict__ K, const float* __restrict__ V,
    const float* __restrict__ Mh, const float* __restrict__ Sh,
    const float* __restrict__ Mw, const float* __restrict__ Sw,
    float* __restrict__ out)
{
    __shared__ float sm[CQK_*W_*2];          // 64 KB: Qr|Kr, then V chunks
    const int bid = blockIdx.x;
    const int b = bid >> 7, h = bid & 127;
    const int t = threadIdx.x;
    {
        const float* Qb = Q + (size_t)b*CQK_*HW_ + h*W_;
        const float* Kb = K + (size_t)b*CQK_*HW_ + h*W_;
        for (int i = t; i < CQK_*W_; i += 256) {
            sm[i]            = Qb[(i >> 7)*HW_ + (i & 127)];
            sm[CQK_*W_ + i]  = Kb[(i >> 7)*HW_ + (i & 127)];
        }
    }
    __syncthreads();
    const int w = t >> 1, vh = t & 1, v0 = vh << 6;
    const int sidx = (b*H_ + h)*W_ + w;
    const float mh = Mh[sidx], mw = Mw[sidx];
    const float M = fmaxf(mh, mw);
    const float invS = 1.f / (Sh[sidx]*__expf(mh - M) + Sw[sidx]*__expf(mw - M));
    float e[64];
    #pragma unroll
    for (int j = 0; j < 64; ++j) e[j] = 0.f;
    for (int c = 0; c < CQK_; ++c) {
        const float qv = sm[(c<<7) + w];
        #pragma unroll
        for (int j = 0; j < 64; ++j) e[j] += qv * sm[CQK_*W_ + (c<<7) + v0 + j];
    }
    #pragma unroll
    for (int j = 0; j < 64; ++j) e[j] = __expf(e[j] - M) * invS;   // att_w
    __syncthreads();
    for (int cc = 0; cc < 3; ++cc) {         // V in 64-channel chunks (32 KB)
        for (int i = t; i < 64*W_; i += 256)
            sm[i] = V[((size_t)b*C_ + cc*64 + (i >> 7))*HW_ + h*W_ + (i & 127)];
        __syncthreads();
        for (int c = 0; c < 64; ++c) {
            float p = 0.f;
            #pragma unroll
            for (int j = 0; j < 64; ++j) p += e[j] * sm[(c<<7) + v0 + j];
            p += __shfl_xor(p, 1);
            if (vh == 0)
                out[((size_t)b*C_ + cc*64 + c)*HW_ + h*W_ + w] = p;
        }
        __syncthreads();
    }
}

// ---- column attention output + final: out = gamma*(out_h + out_w) + x
__global__ __launch_bounds__(256) void koh(
    const float* __restrict__ Q, const float* __restrict__ K, const float* __restrict__ V,
    const float* __restrict__ Mh, const float* __restrict__ Sh,
    const float* __restrict__ Mw, const float* __restrict__ Sw,
    const float* __restrict__ x, const float* __restrict__ gamma,
    float* __restrict__ out)
{
    __shared__ float sm[CQK_*H_*2];          // 64 KB
    const int bid = blockIdx.x;
    const int b = bid & 7, w = bid >> 3;     // batch-per-XCD swizzle
    const int t = threadIdx.x;
    {
        const float* Qb = Q + (size_t)b*CQK_*HW_ + w;
        const float* Kb = K + (size_t)b*CQK_*HW_ + w;
        for (int i = t; i < CQK_*H_; i += 256) {
            const int c = i >> 7, hh = i & 127;
            sm[i]           = Qb[c*HW_ + hh*W_];
            sm[CQK_*H_ + i] = Kb[c*HW_ + hh*W_];
        }
    }
    __syncthreads();
    const int h = t >> 1, gh = t & 1, g0 = gh << 6;
    const int sidx = (b*H_ + h)*W_ + w;
    const float mh = Mh[sidx], mw = Mw[sidx];
    const float M = fmaxf(mh, mw);
    const float invS = 1.f / (Sh[sidx]*__expf(mh - M) + Sw[sidx]*__expf(mw - M));
    const float gam = gamma[0];
    float e[64];
    #pragma unroll
    for (int j = 0; j < 64; ++j) e[j] = 0.f;
    for (int c = 0; c < CQK_; ++c) {
        const float qv = sm[(c<<7) + h];
        #pragma unroll
        for (int j = 0; j < 64; ++j) e[j] += qv * sm[CQK_*H_ + (c<<7) + g0 + j];
    }
    #pragma unroll
    for (int j = 0; j < 64; ++j)
        e[j] = (g0 + j == h) ? 0.f : __expf(e[j] - M) * invS;      // att_h (diag=0)
    __syncthreads();
    for (int cc = 0; cc < 3; ++cc) {
        for (int i = t; i < 64*H_; i += 256)                       // column gather
            sm[i] = V[((size_t)b*C_ + cc*64 + (i >> 7))*HW_ + (i & 127)*W_ + w];
        __syncthreads();
        for (int c = 0; c < 64; ++c) {
            float p = 0.f;
            #pragma unroll
            for (int j = 0; j < 64; ++j) p += e[j] * sm[(c<<7) + g0 + j];
            p += __shfl_xor(p, 1);
            if (gh == 0) {
                const size_t a = ((size_t)b*C_ + cc*64 + c)*HW_ + h*W_ + w;
                out[a] = gam * (p + out[a]) + x[a];                // final combine
            }
        }
        __syncthreads();
    }
}

extern "C" void kernel_launch(void* const* d_in, const int* in_sizes, int n_in,
                              void* d_out, int out_size, void* d_ws, size_t ws_size,
                              hipStream_t stream)
{
    const float* x  = (const float*)d_in[0];
    const float* Wq = (const float*)d_in[1];
    const float* bq = (const float*)d_in[2];
    const float* Wk = (const float*)d_in[3];
    const float* bk = (const float*)d_in[4];
    const float* Wv = (const float*)d_in[5];
    const float* bv = (const float*)d_in[6];
    const float* gm = (const float*)d_in[7];
    float* out = (float*)d_out;
    float* ws  = (float*)d_ws;

    float* Q  = ws;                  // 8*64*16384
    float* K  = ws + 8388608;
    float* V  = ws + 16777216;       // 8*192*16384
    float* Mh = ws + 41943040;
    float* Sh = Mh + 131072;
    float* Mw = Sh + 131072;
    float* Sw = Mw + 131072;

    hipLaunchKernelGGL(kproj, dim3(2048), dim3(256), 0, stream,
                       x, Wq, bq, Wk, bk, Wv, bv, Q, K, V);
    hipLaunchKernelGGL(kch,  dim3(1024), dim3(256), 0, stream, Q, K, Mh, Sh);
    hipLaunchKernelGGL(kcw,  dim3(1024), dim3(256), 0, stream, Q, K, Mw, Sw);
    hipLaunchKernelGGL(kow,  dim3(1024), dim3(256), 0, stream,
                       Q, K, V, Mh, Sh, Mw, Sw, out);
    hipLaunchKernelGGL(koh,  dim3(1024), dim3(256), 0, stream,
                       Q, K, V, Mh, Sh, Mw, Sw, x, gm, out);
}

// Round 2
// 529.669 us; speedup vs baseline: 2.6120x; 2.6120x over previous
//
#include <hip/hip_runtime.h>
#include <math.h>

// RCC criss-cross attention, MFMA-bf16 pipeline. B=8, C=192, CQK=64, H=W=128.
//
//  kproj : Q,K -> bf16 [b][w][h][c] (channel-last), V -> bf16 [b][c][h][w]
//  ktrv  : V transpose -> Vc bf16 [b][c][w][h]
//  kC    : per (b,w): e_h MFMA (diag mask) -> Mh,Sh; P=exp(e-Mh) -> PV MFMA
//          -> raw O2 [b][w][h][c] bf16
//  kR    : per (b,h): e_w MFMA -> Mw,Sw (local); P -> swapped PV mfma(V,P)
//          -> merge stats with Mh,Sh, out = gamma*(O1*sw + O2*sh) + x
//
// All MFMA LDS tiles: rows with 16B chunks, swizzle chunk^=(row&7) on both
// write and read. mfma_f32_16x16x32_bf16 fragments:
//   A: row=lane&15, k=8*(lane>>4)+e   B: col=lane&15, k=8*(lane>>4)+e
//   D: col=lane&15, row=4*(lane>>4)+reg   (m89/m91-verified)

#define B_   8
#define C_   192
#define CQK_ 64
#define H_   128
#define W_   128
#define HW_  (H_*W_)

typedef unsigned short u16;
typedef __attribute__((ext_vector_type(8))) short  s16x8;
typedef __attribute__((ext_vector_type(4))) float  f32x4;
#define MFMA_BF16 __builtin_amdgcn_mfma_f32_16x16x32_bf16

__device__ __forceinline__ u16 f2b(float f) {
    unsigned u = __float_as_uint(f);
    return (u16)((u + 0x7fffu + ((u >> 16) & 1u)) >> 16);   // RNE
}
__device__ __forceinline__ float b2f(u16 v) {
    return __uint_as_float(((unsigned)v) << 16);
}

// ---------------------------------------------------------------- projection
// VALU fp32 compute (no fp32 MFMA on CDNA4); bf16 outputs.
__global__ __launch_bounds__(256) void kproj(
    const float* __restrict__ x,
    const float* __restrict__ Wq, const float* __restrict__ bq,
    const float* __restrict__ Wk, const float* __restrict__ bk,
    const float* __restrict__ Wv, const float* __restrict__ bv,
    u16* __restrict__ Qc, u16* __restrict__ Kc, u16* __restrict__ Vn)
{
    __shared__ float xs[C_*64];              // 48 KB
    const int n0  = blockIdx.x << 6;         // 64-position tile
    const int b   = n0 >> 14;
    const int hw0 = n0 & (HW_-1);
    const int h   = hw0 >> 7;
    const int w0  = hw0 & 127;               // 0 or 64
    const float* xb = x + (size_t)b*C_*HW_ + hw0;
    const int t = threadIdx.x;
    for (int i = t; i < C_*64; i += 256)
        xs[i] = xb[(i >> 6)*HW_ + (i & 63)];
    __syncthreads();
    const int w  = t & 63;
    const int og = t >> 6;
    for (int ob = 0; ob < 10; ++ob) {
        const int o0 = __builtin_amdgcn_readfirstlane(og*80 + ob*8);
        const float *wb, *bb; int oo;
        if (o0 < 64)       { wb = Wq; bb = bq; oo = o0;       }
        else if (o0 < 128) { wb = Wk; bb = bk; oo = o0 - 64;  }
        else               { wb = Wv; bb = bv; oo = o0 - 128; }
        const float* wr = wb + oo*C_;
        float acc[8];
        #pragma unroll
        for (int j = 0; j < 8; ++j) acc[j] = bb[oo+j];
        for (int c = 0; c < C_; ++c) {
            const float xv = xs[(c<<6) + w];
            #pragma unroll
            for (int j = 0; j < 8; ++j) acc[j] += wr[j*C_ + c] * xv;
        }
        if (o0 < 128) {                      // Q,K channel-last [b][w][h][c]
            s16x8 pk;
            #pragma unroll
            for (int j = 0; j < 8; ++j) pk[j] = (short)f2b(acc[j]);
            u16* dst = (o0 < 64 ? Qc : Kc) +
                       ((size_t)((b*W_ + w0 + w)*H_ + h))*CQK_ + oo;
            *(s16x8*)(void*)dst = pk;
        } else {                             // V natural [b][c][h][w]
            #pragma unroll
            for (int j = 0; j < 8; ++j)
                Vn[(size_t)(b*C_ + oo + j)*HW_ + hw0 + w] = f2b(acc[j]);
        }
    }
}

// ------------------------------------------- V transpose: [c][h][w]->[c][w][h]
__global__ __launch_bounds__(256) void ktrv(
    const u16* __restrict__ Vn, u16* __restrict__ Vc)
{
    __shared__ u16 T[128*128];               // swizzled tile, 256B rows
    const int c = blockIdx.x, b = blockIdx.y;
    const u16* src = Vn + (size_t)(b*C_ + c)*HW_;
    u16*       dst = Vc + (size_t)(b*C_ + c)*HW_;
    const int t = threadIdx.x;
    for (int idx = t; idx < 128*16; idx += 256) {
        const int hh = idx >> 4, o = idx & 15;
        s16x8 v = *(const s16x8*)(void*)(src + hh*128 + o*8);
        *(s16x8*)(void*)(T + hh*128 + ((o ^ (hh & 7)) << 3)) = v;
    }
    __syncthreads();
    const int w = t & 127, half = t >> 7;
    for (int seg = 0; seg < 8; ++seg) {
        const int h0 = half*64 + seg*8;
        s16x8 pk;
        #pragma unroll
        for (int k = 0; k < 8; ++k) {
            const int hh = h0 + k;
            const int chunk = (w >> 3) ^ (hh & 7);
            pk[k] = (short)T[hh*128 + (chunk << 3) + (w & 7)];
        }
        *(s16x8*)(void*)(dst + w*128 + h0) = pk;
    }
}

// ------------------- column attention (per b,w): O2 raw + Mh,Sh  [512 thr]
__global__ __launch_bounds__(512) void kC(
    const u16* __restrict__ Qc, const u16* __restrict__ Kc,
    const u16* __restrict__ Vc,
    u16* __restrict__ O2, float* __restrict__ Mh, float* __restrict__ Sh)
{
    extern __shared__ char smem[];
    char* ldsQ = smem;                       // 16KB rows h:128B (-> P 256B)
    char* ldsK = smem + 16384;
    char* ldsP = smem;                       // 32KB, reuses Q|K after scores
    char* ldsV = smem + 32768;               // 48KB rows c:256B
    const int w = blockIdx.x, b = blockIdx.y;
    const int t = threadIdx.x, lane = t & 63, wid = t >> 6;
    const int l15 = lane & 15, q = lane >> 4;

    // ---- stage Q,K (contiguous 16KB slices) + Vc slice
    {
        const u16* qs = Qc + (size_t)(b*W_ + w)*H_*CQK_;
        const u16* ks = Kc + (size_t)(b*W_ + w)*H_*CQK_;
        for (int idx = t; idx < 1024; idx += 512) {
            const int r = idx >> 3, o = idx & 7, so = ((o ^ (r & 7)) << 4);
            *(s16x8*)(ldsQ + r*128 + so) = *(const s16x8*)(void*)(qs + idx*8);
            *(s16x8*)(ldsK + r*128 + so) = *(const s16x8*)(void*)(ks + idx*8);
        }
        for (int idx = t; idx < 3072; idx += 512) {
            const int c = idx >> 4, o = idx & 15;
            s16x8 v = *(const s16x8*)(void*)
                      (Vc + ((size_t)(b*C_ + c)*W_ + w)*H_ + o*8);
            *(s16x8*)(ldsV + c*256 + ((o ^ (c & 7)) << 4)) = v;
        }
    }
    __syncthreads();

    // ---- scores: e_h[h][g] = sum_c Q[h][c] K[g][c]
    f32x4 accS[8];
    #pragma unroll
    for (int i = 0; i < 8; ++i) accS[i] = (f32x4){0.f,0.f,0.f,0.f};
    const int arow = (wid << 4) + l15;
    #pragma unroll
    for (int ks = 0; ks < 2; ++ks) {
        const int ch = ks*4 + q;
        s16x8 af = *(const s16x8*)(ldsQ + arow*128 + ((ch ^ (arow & 7)) << 4));
        #pragma unroll
        for (int gt = 0; gt < 8; ++gt) {
            const int br = (gt << 4) + l15;
            s16x8 bf = *(const s16x8*)(ldsK + br*128 + ((ch ^ (br & 7)) << 4));
            accS[gt] = MFMA_BF16(af, bf, accS[gt], 0, 0, 0);
        }
    }
    __syncthreads();                         // QK reads done; P may overwrite

    // ---- diag mask, row stats, P = exp(e - Mh)
    #pragma unroll
    for (int r = 0; r < 4; ++r) {
        const int hh = (wid << 4) + (q << 2) + r;
        #pragma unroll
        for (int gt = 0; gt < 8; ++gt)
            if ((gt << 4) + l15 == hh) accS[gt][r] = -3.0e38f;
        float m = -3.0e38f;
        #pragma unroll
        for (int gt = 0; gt < 8; ++gt) m = fmaxf(m, accS[gt][r]);
        m = fmaxf(m, __shfl_xor(m, 1)); m = fmaxf(m, __shfl_xor(m, 2));
        m = fmaxf(m, __shfl_xor(m, 4)); m = fmaxf(m, __shfl_xor(m, 8));
        float s = 0.f;
        #pragma unroll
        for (int gt = 0; gt < 8; ++gt) {
            const float e = __expf(accS[gt][r] - m);
            s += e;
            const int g = (gt << 4) + l15;
            *(u16*)(ldsP + hh*256 + (((g >> 3) ^ (hh & 7)) << 4) + (g & 7)*2)
                = f2b(e);
        }
        s += __shfl_xor(s, 1); s += __shfl_xor(s, 2);
        s += __shfl_xor(s, 4); s += __shfl_xor(s, 8);
        if (l15 == 0) {
            Mh[(b*W_ + w)*H_ + hh] = m;
            Sh[(b*W_ + w)*H_ + hh] = s;
        }
    }
    __syncthreads();

    // ---- PV: O2[h][c] = sum_g P[h][g] V[c][g]
    f32x4 accO[12];
    #pragma unroll
    for (int i = 0; i < 12; ++i) accO[i] = (f32x4){0.f,0.f,0.f,0.f};
    #pragma unroll
    for (int ks = 0; ks < 4; ++ks) {
        const int ch = ks*4 + q;
        const int pr = (wid << 4) + l15;     // A = P, row = h
        s16x8 af = *(const s16x8*)(ldsP + pr*256 + ((ch ^ (pr & 7)) << 4));
        #pragma unroll
        for (int ct = 0; ct < 12; ++ct) {
            const int vr = (ct << 4) + l15;  // B = V, col = c
            s16x8 bf = *(const s16x8*)(ldsV + vr*256 + ((ch ^ (vr & 7)) << 4));
            accO[ct] = MFMA_BF16(af, bf, accO[ct], 0, 0, 0);
        }
    }
    // ---- write raw O2 [b][w][h][c] bf16
    #pragma unroll
    for (int ct = 0; ct < 12; ++ct) {
        const int c = (ct << 4) + l15;
        #pragma unroll
        for (int r = 0; r < 4; ++r) {
            const int hh = (wid << 4) + (q << 2) + r;
            O2[((size_t)(b*W_ + w)*H_ + hh)*C_ + c] = f2b(accO[ct][r]);
        }
    }
}

// -------- row attention + fused final (per b,h)  [512 thr, 132KB LDS]
__global__ __launch_bounds__(512) void kR(
    const u16* __restrict__ Qc, const u16* __restrict__ Kc,
    const u16* __restrict__ Vn, const u16* __restrict__ O2,
    const float* __restrict__ Mh, const float* __restrict__ Sh,
    const float* __restrict__ x, const float* __restrict__ gamma,
    float* __restrict__ out)
{
    extern __shared__ char smem[];
    char*  ldsQ  = smem;                     // 16KB rows w:128B
    char*  ldsK  = smem + 16384;
    char*  ldsP  = smem;                     // 32KB rows w:256B (reuse)
    char*  ldsV  = smem + 32768;             // 48KB rows c:256B
    char*  ldsO2 = smem + 81920;             // 128 rows * 400B (no swizzle)
    float* sMh = (float*)(smem + 133120);
    float* sSh = sMh + 128;
    float* sMw = sSh + 128;
    float* sSw = sMw + 128;
    const int h = blockIdx.x, b = blockIdx.y;
    const int t = threadIdx.x, lane = t & 63, wid = t >> 6;
    const int l15 = lane & 15, q = lane >> 4;
    const float gam = gamma[0];

    // ---- stage: Q,K rows (strided 128B), V slice, O2 slice, Mh/Sh
    for (int idx = t; idx < 1024; idx += 512) {
        const int r = idx >> 3, o = idx & 7, so = ((o ^ (r & 7)) << 4);
        const size_t g = ((size_t)(b*W_ + r)*H_ + h)*CQK_ + o*8;
        *(s16x8*)(ldsQ + r*128 + so) = *(const s16x8*)(void*)(Qc + g);
        *(s16x8*)(ldsK + r*128 + so) = *(const s16x8*)(void*)(Kc + g);
    }
    for (int idx = t; idx < 3072; idx += 512) {
        const int c = idx >> 4, o = idx & 15;
        s16x8 v = *(const s16x8*)(void*)
                  (Vn + (size_t)(b*C_ + c)*HW_ + h*W_ + o*8);
        *(s16x8*)(ldsV + c*256 + ((o ^ (c & 7)) << 4)) = v;
    }
    for (int idx = t; idx < 3200; idx += 512) {
        const int r = idx / 25, o = idx - r*25;
        if (o < 24) {
            s16x8 v = *(const s16x8*)(void*)
                      (O2 + ((size_t)(b*W_ + r)*H_ + h)*C_ + o*8);
            *(s16x8*)(ldsO2 + r*400 + o*16) = v;
        }
    }
    if (t < 128) {
        sMh[t] = Mh[(b*W_ + t)*H_ + h];
        sSh[t] = Sh[(b*W_ + t)*H_ + h];
    }
    __syncthreads();

    // ---- scores: e_w[w][v] = sum_c Q[w][c] K[v][c]
    f32x4 accS[8];
    #pragma unroll
    for (int i = 0; i < 8; ++i) accS[i] = (f32x4){0.f,0.f,0.f,0.f};
    const int arow = (wid << 4) + l15;
    #pragma unroll
    for (int ks = 0; ks < 2; ++ks) {
        const int ch = ks*4 + q;
        s16x8 af = *(const s16x8*)(ldsQ + arow*128 + ((ch ^ (arow & 7)) << 4));
        #pragma unroll
        for (int vt = 0; vt < 8; ++vt) {
            const int br = (vt << 4) + l15;
            s16x8 bf = *(const s16x8*)(ldsK + br*128 + ((ch ^ (br & 7)) << 4));
            accS[vt] = MFMA_BF16(af, bf, accS[vt], 0, 0, 0);
        }
    }
    __syncthreads();

    // ---- row stats + P = exp(e - Mw)
    #pragma unroll
    for (int r = 0; r < 4; ++r) {
        const int ww = (wid << 4) + (q << 2) + r;
        float m = -3.0e38f;
        #pragma unroll
        for (int vt = 0; vt < 8; ++vt) m = fmaxf(m, accS[vt][r]);
        m = fmaxf(m, __shfl_xor(m, 1)); m = fmaxf(m, __shfl_xor(m, 2));
        m = fmaxf(m, __shfl_xor(m, 4)); m = fmaxf(m, __shfl_xor(m, 8));
        float s = 0.f;
        #pragma unroll
        for (int vt = 0; vt < 8; ++vt) {
            const float e = __expf(accS[vt][r] - m);
            s += e;
            const int v = (vt << 4) + l15;
            *(u16*)(ldsP + ww*256 + (((v >> 3) ^ (ww & 7)) << 4) + (v & 7)*2)
                = f2b(e);
        }
        s += __shfl_xor(s, 1); s += __shfl_xor(s, 2);
        s += __shfl_xor(s, 4); s += __shfl_xor(s, 8);
        if (l15 == 0) { sMw[ww] = m; sSw[ww] = s; }
    }
    __syncthreads();

    // ---- PV swapped: D[c][w] = sum_v V[c][v] P[w][v]  (A=V, B=P)
    f32x4 accO[12];
    #pragma unroll
    for (int i = 0; i < 12; ++i) accO[i] = (f32x4){0.f,0.f,0.f,0.f};
    const int prow = (wid << 4) + l15;       // B col = w
    #pragma unroll
    for (int ks = 0; ks < 4; ++ks) {
        const int ch = ks*4 + q;
        s16x8 bfp = *(const s16x8*)(ldsP + prow*256 + ((ch ^ (prow & 7)) << 4));
        #pragma unroll
        for (int ct = 0; ct < 12; ++ct) {
            const int vr = (ct << 4) + l15;  // A row = c
            s16x8 afv = *(const s16x8*)(ldsV + vr*256 + ((ch ^ (vr & 7)) << 4));
            accO[ct] = MFMA_BF16(afv, bfp, accO[ct], 0, 0, 0);
        }
    }

    // ---- epilogue: merge stats, out = gam*(O1*sw + O2*sh) + x
    const int ww = (wid << 4) + l15;         // this lane's w (D col)
    const float mh = sMh[ww], shv = sSh[ww];
    const float mw = sMw[ww], swv = sSw[ww];
    const float M  = fmaxf(mh, mw);
    const float S  = shv*__expf(mh - M) + swv*__expf(mw - M);
    const float scw = __expf(mw - M) / S;
    const float sch = __expf(mh - M) / S;
    const size_t gb = (size_t)b*C_*HW_ + h*W_ + ww;
    #pragma unroll
    for (int ct = 0; ct < 12; ++ct) {
        #pragma unroll
        for (int r = 0; r < 4; ++r) {
            const int c = (ct << 4) + (q << 2) + r;
            const float o2 = b2f(*(const u16*)(ldsO2 + ww*400 + c*2));
            const size_t ga = gb + (size_t)c*HW_;
            out[ga] = gam*(accO[ct][r]*scw + o2*sch) + x[ga];
        }
    }
}

extern "C" void kernel_launch(void* const* d_in, const int* in_sizes, int n_in,
                              void* d_out, int out_size, void* d_ws, size_t ws_size,
                              hipStream_t stream)
{
    const float* x  = (const float*)d_in[0];
    const float* Wq = (const float*)d_in[1];
    const float* bq = (const float*)d_in[2];
    const float* Wk = (const float*)d_in[3];
    const float* bk = (const float*)d_in[4];
    const float* Wv = (const float*)d_in[5];
    const float* bv = (const float*)d_in[6];
    const float* gm = (const float*)d_in[7];
    float* out = (float*)d_out;

    u16* Qc = (u16*)d_ws;                    // 8M elems
    u16* Kc = Qc + 8388608;
    u16* Vn = Kc + 8388608;                  // 25.2M
    u16* Vc = Vn + 25165824;
    u16* O2 = Vc + 25165824;
    float* Mh = (float*)(O2 + 25165824);     // 131072 each
    float* Sh = Mh + 131072;

    hipLaunchKernelGGL(kproj, dim3(2048), dim3(256), 0, stream,
                       x, Wq, bq, Wk, bk, Wv, bv, Qc, Kc, Vn);
    hipLaunchKernelGGL(ktrv, dim3(C_, B_), dim3(256), 0, stream, Vn, Vc);
    hipLaunchKernelGGL(kC, dim3(W_, B_), dim3(512), 81920, stream,
                       Qc, Kc, Vc, O2, Mh, Sh);
    hipLaunchKernelGGL(kR, dim3(H_, B_), dim3(512), 135168, stream,
                       Qc, Kc, Vn, O2, Mh, Sh, x, gm, out);
}

// Round 3
// 244.202 us; speedup vs baseline: 5.6654x; 2.1690x over previous
//
#include <hip/hip_runtime.h>
#include <math.h>

// RCC criss-cross attention, MFMA-bf16 pipeline. B=8, C=192, CQK=64, H=W=128.
//
//  kwcast : Wq|Wk|Wv fp32 -> Wb bf16, pre-swizzled per-phase LDS image; bias
//  kprojM : MFMA GEMM  D[w][o] = sum_c X[c][w] W[o][c] + b[o], per (b,h) row
//           -> Qc,Kc bf16 [b][w][h][c] channel-last, Vn bf16 [b][c][h][w]
//  ktrv   : V transpose -> Vc bf16 [b][c][w][h]
//  kC     : per (b,w): e_h MFMA (diag mask) -> Mh,Sh; P=exp(e-Mh) -> PV MFMA
//           -> raw O2 [b][w][h][c] bf16
//  kR     : per (b,h): e_w MFMA -> Mw,Sw local; P -> swapped PV mfma(V,P)
//           -> merge stats, out = gamma*(O1*sw + O2*sh) + x
//
// MFMA LDS tiles: rows of 16B chunks, swizzle chunk ^= (row&7) on write+read.
// mfma_f32_16x16x32_bf16 fragments:
//   A: row=lane&15, k=8*(lane>>4)+e   B: col=lane&15, k=8*(lane>>4)+e
//   D: col=lane&15, row=4*(lane>>4)+reg

#define B_   8
#define C_   192
#define CQK_ 64
#define H_   128
#define W_   128
#define HW_  (H_*W_)

typedef unsigned short u16;
typedef __attribute__((ext_vector_type(8))) short  s16x8;
typedef __attribute__((ext_vector_type(4))) float  f32x4;
#define MFMA_BF16 __builtin_amdgcn_mfma_f32_16x16x32_bf16

__device__ __forceinline__ u16 f2b(float f) {
    unsigned u = __float_as_uint(f);
    return (u16)((u + 0x7fffu + ((u >> 16) & 1u)) >> 16);   // RNE
}
__device__ __forceinline__ float b2f(u16 v) {
    return __uint_as_float(((unsigned)v) << 16);
}

// ------------------------------------------------ W -> bf16 pre-swizzled + bias
// Wb[p][o][chunk][8]: p = K-phase (c = p*64 + cc), chunk = (cc>>3)^(o&7).
__global__ __launch_bounds__(256) void kwcast(
    const float* __restrict__ Wq, const float* __restrict__ bq,
    const float* __restrict__ Wk, const float* __restrict__ bk,
    const float* __restrict__ Wv, const float* __restrict__ bv,
    u16* __restrict__ Wb, float* __restrict__ Bb)
{
    const int o = blockIdx.x;                // 320 rows
    const float *row, *bias; int oo;
    if (o < 64)        { row = Wq; bias = bq; oo = o;       }
    else if (o < 128)  { row = Wk; bias = bk; oo = o - 64;  }
    else               { row = Wv; bias = bv; oo = o - 128; }
    const int t = threadIdx.x;
    if (t < C_) {
        const int p = t >> 6, cc = t & 63;
        Wb[p*20480 + o*64 + (((cc >> 3) ^ (o & 7)) << 3) + (cc & 7)]
            = f2b(row[oo*C_ + t]);
    }
    if (t == C_) Bb[o] = bias[oo];
}

// ---------------------------------------------------- MFMA projection GEMM
// Per (h,b): tile 128 w-rows x 320 o-cols, K=192 in 3 phases of 64.
__global__ __launch_bounds__(256, 2) void kprojM(
    const float* __restrict__ x,
    const u16* __restrict__ Wb, const float* __restrict__ Bb,
    u16* __restrict__ Qc, u16* __restrict__ Kc, u16* __restrict__ Vn)
{
    __shared__ u16 lds[28672];               // 56 KB
    u16* ldsW = lds;                         // 320 rows x 128B (chunk-swizzled)
    u16* ldsA = lds + 20480;                 // 128 rows x 128B
    const int h = blockIdx.x, b = blockIdx.y;
    const int t = threadIdx.x, lane = t & 63, wid = t >> 6;
    const int l15 = lane & 15, q = lane >> 4;
    const float* xb = x + (size_t)b*C_*HW_ + h*W_;
    const int colbase = wid*80;              // wave owns 80 o-cols

    f32x4 acc[8][5];
    #pragma unroll
    for (int ct = 0; ct < 5; ++ct) {
        const float bv = Bb[colbase + ct*16 + l15];
        #pragma unroll
        for (int r = 0; r < 8; ++r) acc[r][ct] = (f32x4){bv, bv, bv, bv};
    }

    const int wql = t & 127, cpair = (t >> 7) << 1;
    for (int p = 0; p < 3; ++p) {
        __syncthreads();                     // prev compute done
        // ---- stage W chunk (pre-swizzled -> linear copy, conflict-free)
        {
            const u16* ws = Wb + p*20480 + t*8;
            #pragma unroll
            for (int i = 0; i < 10; ++i)
                *(s16x8*)(void*)(ldsA - 20480 + /*ldsW*/ (t*8 + i*2048)) =
                    *(const s16x8*)(void*)(ws + i*2048);
        }
        // ---- stage A: x fp32 -> bf16, LDS [w][c] swizzled (u32-packed)
        #pragma unroll
        for (int i = 0; i < 16; ++i) {
            const int c = i*4 + cpair;       // c, c+1
            const float v0 = xb[(size_t)(p*64 + c    )*HW_ + wql];
            const float v1 = xb[(size_t)(p*64 + c + 1)*HW_ + wql];
            const unsigned pk = (unsigned)f2b(v0) | ((unsigned)f2b(v1) << 16);
            *(unsigned*)(void*)(ldsA + wql*64 + (((c >> 3) ^ (wql & 7)) << 3)
                                + (c & 7)) = pk;
        }
        __syncthreads();
        // ---- MFMA: K-chunk 64 = 2 sub-steps of 32
        #pragma unroll
        for (int ks = 0; ks < 2; ++ks) {
            s16x8 bf[5];
            #pragma unroll
            for (int ct = 0; ct < 5; ++ct) {
                const int o = colbase + ct*16 + l15;
                bf[ct] = *(const s16x8*)(void*)
                         (ldsW + o*64 + ((((ks << 2) + q) ^ (o & 7)) << 3));
            }
            #pragma unroll
            for (int r = 0; r < 8; ++r) {
                const int w = r*16 + l15;
                const s16x8 af = *(const s16x8*)(void*)
                    (ldsA + w*64 + ((((ks << 2) + q) ^ (w & 7)) << 3));
                #pragma unroll
                for (int ct = 0; ct < 5; ++ct)
                    acc[r][ct] = MFMA_BF16(af, bf[ct], acc[r][ct], 0, 0, 0);
            }
        }
    }
    // ---- epilogue: route by output group (wave-uniform per ct)
    #pragma unroll
    for (int ct = 0; ct < 5; ++ct) {
        const int og = colbase + ct*16;
        const int o  = og + l15;
        #pragma unroll
        for (int r = 0; r < 8; ++r) {
            #pragma unroll
            for (int reg = 0; reg < 4; ++reg) {
                const int w = r*16 + q*4 + reg;
                const u16 bv = f2b(acc[r][ct][reg]);
                if (og < 64)
                    Qc[((size_t)(b*W_ + w)*H_ + h)*CQK_ + o] = bv;
                else if (og < 128)
                    Kc[((size_t)(b*W_ + w)*H_ + h)*CQK_ + (o - 64)] = bv;
                else
                    Vn[(size_t)(b*C_ + (o - 128))*HW_ + h*W_ + w] = bv;
            }
        }
    }
}

// ------------------------------------------- V transpose: [c][h][w]->[c][w][h]
__global__ __launch_bounds__(256) void ktrv(
    const u16* __restrict__ Vn, u16* __restrict__ Vc)
{
    __shared__ u16 T[128*128];
    const int c = blockIdx.x, b = blockIdx.y;
    const u16* src = Vn + (size_t)(b*C_ + c)*HW_;
    u16*       dst = Vc + (size_t)(b*C_ + c)*HW_;
    const int t = threadIdx.x;
    for (int idx = t; idx < 128*16; idx += 256) {
        const int hh = idx >> 4, o = idx & 15;
        s16x8 v = *(const s16x8*)(void*)(src + hh*128 + o*8);
        *(s16x8*)(void*)(T + hh*128 + ((o ^ (hh & 7)) << 3)) = v;
    }
    __syncthreads();
    const int w = t & 127, half = t >> 7;
    for (int seg = 0; seg < 8; ++seg) {
        const int h0 = half*64 + seg*8;
        s16x8 pk;
        #pragma unroll
        for (int k = 0; k < 8; ++k) {
            const int hh = h0 + k;
            const int chunk = (w >> 3) ^ (hh & 7);
            pk[k] = (short)T[hh*128 + (chunk << 3) + (w & 7)];
        }
        *(s16x8*)(void*)(dst + w*128 + h0) = pk;
    }
}

// ------------------- column attention (per b,w): O2 raw + Mh,Sh  [512 thr]
__global__ __launch_bounds__(512) void kC(
    const u16* __restrict__ Qc, const u16* __restrict__ Kc,
    const u16* __restrict__ Vc,
    u16* __restrict__ O2, float* __restrict__ Mh, float* __restrict__ Sh)
{
    extern __shared__ char smem[];
    char* ldsQ = smem;
    char* ldsK = smem + 16384;
    char* ldsP = smem;
    char* ldsV = smem + 32768;
    const int w = blockIdx.x, b = blockIdx.y;
    const int t = threadIdx.x, lane = t & 63, wid = t >> 6;
    const int l15 = lane & 15, q = lane >> 4;

    {
        const u16* qs = Qc + (size_t)(b*W_ + w)*H_*CQK_;
        const u16* ks = Kc + (size_t)(b*W_ + w)*H_*CQK_;
        for (int idx = t; idx < 1024; idx += 512) {
            const int r = idx >> 3, o = idx & 7, so = ((o ^ (r & 7)) << 4);
            *(s16x8*)(ldsQ + r*128 + so) = *(const s16x8*)(void*)(qs + idx*8);
            *(s16x8*)(ldsK + r*128 + so) = *(const s16x8*)(void*)(ks + idx*8);
        }
        for (int idx = t; idx < 3072; idx += 512) {
            const int c = idx >> 4, o = idx & 15;
            s16x8 v = *(const s16x8*)(void*)
                      (Vc + ((size_t)(b*C_ + c)*W_ + w)*H_ + o*8);
            *(s16x8*)(ldsV + c*256 + ((o ^ (c & 7)) << 4)) = v;
        }
    }
    __syncthreads();

    f32x4 accS[8];
    #pragma unroll
    for (int i = 0; i < 8; ++i) accS[i] = (f32x4){0.f,0.f,0.f,0.f};
    const int arow = (wid << 4) + l15;
    #pragma unroll
    for (int ks = 0; ks < 2; ++ks) {
        const int ch = ks*4 + q;
        s16x8 af = *(const s16x8*)(ldsQ + arow*128 + ((ch ^ (arow & 7)) << 4));
        #pragma unroll
        for (int gt = 0; gt < 8; ++gt) {
            const int br = (gt << 4) + l15;
            s16x8 bf = *(const s16x8*)(ldsK + br*128 + ((ch ^ (br & 7)) << 4));
            accS[gt] = MFMA_BF16(af, bf, accS[gt], 0, 0, 0);
        }
    }
    __syncthreads();

    #pragma unroll
    for (int r = 0; r < 4; ++r) {
        const int hh = (wid << 4) + (q << 2) + r;
        #pragma unroll
        for (int gt = 0; gt < 8; ++gt)
            if ((gt << 4) + l15 == hh) accS[gt][r] = -3.0e38f;
        float m = -3.0e38f;
        #pragma unroll
        for (int gt = 0; gt < 8; ++gt) m = fmaxf(m, accS[gt][r]);
        m = fmaxf(m, __shfl_xor(m, 1)); m = fmaxf(m, __shfl_xor(m, 2));
        m = fmaxf(m, __shfl_xor(m, 4)); m = fmaxf(m, __shfl_xor(m, 8));
        float s = 0.f;
        #pragma unroll
        for (int gt = 0; gt < 8; ++gt) {
            const float e = __expf(accS[gt][r] - m);
            s += e;
            const int g = (gt << 4) + l15;
            *(u16*)(ldsP + hh*256 + (((g >> 3) ^ (hh & 7)) << 4) + (g & 7)*2)
                = f2b(e);
        }
        s += __shfl_xor(s, 1); s += __shfl_xor(s, 2);
        s += __shfl_xor(s, 4); s += __shfl_xor(s, 8);
        if (l15 == 0) {
            Mh[(b*W_ + w)*H_ + hh] = m;
            Sh[(b*W_ + w)*H_ + hh] = s;
        }
    }
    __syncthreads();

    f32x4 accO[12];
    #pragma unroll
    for (int i = 0; i < 12; ++i) accO[i] = (f32x4){0.f,0.f,0.f,0.f};
    #pragma unroll
    for (int ks = 0; ks < 4; ++ks) {
        const int ch = ks*4 + q;
        const int pr = (wid << 4) + l15;
        s16x8 af = *(const s16x8*)(ldsP + pr*256 + ((ch ^ (pr & 7)) << 4));
        #pragma unroll
        for (int ct = 0; ct < 12; ++ct) {
            const int vr = (ct << 4) + l15;
            s16x8 bf = *(const s16x8*)(ldsV + vr*256 + ((ch ^ (vr & 7)) << 4));
            accO[ct] = MFMA_BF16(af, bf, accO[ct], 0, 0, 0);
        }
    }
    #pragma unroll
    for (int ct = 0; ct < 12; ++ct) {
        const int c = (ct << 4) + l15;
        #pragma unroll
        for (int r = 0; r < 4; ++r) {
            const int hh = (wid << 4) + (q << 2) + r;
            O2[((size_t)(b*W_ + w)*H_ + hh)*C_ + c] = f2b(accO[ct][r]);
        }
    }
}

// -------- row attention + fused final (per b,h)  [512 thr, 132KB LDS]
__global__ __launch_bounds__(512) void kR(
    const u16* __restrict__ Qc, const u16* __restrict__ Kc,
    const u16* __restrict__ Vn, const u16* __restrict__ O2,
    const float* __restrict__ Mh, const float* __restrict__ Sh,
    const float* __restrict__ x, const float* __restrict__ gamma,
    float* __restrict__ out)
{
    extern __shared__ char smem[];
    char*  ldsQ  = smem;
    char*  ldsK  = smem + 16384;
    char*  ldsP  = smem;
    char*  ldsV  = smem + 32768;
    char*  ldsO2 = smem + 81920;
    float* sMh = (float*)(smem + 133120);
    float* sSh = sMh + 128;
    float* sMw = sSh + 128;
    float* sSw = sMw + 128;
    const int h = blockIdx.x, b = blockIdx.y;
    const int t = threadIdx.x, lane = t & 63, wid = t >> 6;
    const int l15 = lane & 15, q = lane >> 4;
    const float gam = gamma[0];

    for (int idx = t; idx < 1024; idx += 512) {
        const int r = idx >> 3, o = idx & 7, so = ((o ^ (r & 7)) << 4);
        const size_t g = ((size_t)(b*W_ + r)*H_ + h)*CQK_ + o*8;
        *(s16x8*)(ldsQ + r*128 + so) = *(const s16x8*)(void*)(Qc + g);
        *(s16x8*)(ldsK + r*128 + so) = *(const s16x8*)(void*)(Kc + g);
    }
    for (int idx = t; idx < 3072; idx += 512) {
        const int c = idx >> 4, o = idx & 15;
        s16x8 v = *(const s16x8*)(void*)
                  (Vn + (size_t)(b*C_ + c)*HW_ + h*W_ + o*8);
        *(s16x8*)(ldsV + c*256 + ((o ^ (c & 7)) << 4)) = v;
    }
    for (int idx = t; idx < 3200; idx += 512) {
        const int r = idx / 25, o = idx - r*25;
        if (o < 24) {
            s16x8 v = *(const s16x8*)(void*)
                      (O2 + ((size_t)(b*W_ + r)*H_ + h)*C_ + o*8);
            *(s16x8*)(ldsO2 + r*400 + o*16) = v;
        }
    }
    if (t < 128) {
        sMh[t] = Mh[(b*W_ + t)*H_ + h];
        sSh[t] = Sh[(b*W_ + t)*H_ + h];
    }
    __syncthreads();

    f32x4 accS[8];
    #pragma unroll
    for (int i = 0; i < 8; ++i) accS[i] = (f32x4){0.f,0.f,0.f,0.f};
    const int arow = (wid << 4) + l15;
    #pragma unroll
    for (int ks = 0; ks < 2; ++ks) {
        const int ch = ks*4 + q;
        s16x8 af = *(const s16x8*)(ldsQ + arow*128 + ((ch ^ (arow & 7)) << 4));
        #pragma unroll
        for (int vt = 0; vt < 8; ++vt) {
            const int br = (vt << 4) + l15;
            s16x8 bf = *(const s16x8*)(ldsK + br*128 + ((ch ^ (br & 7)) << 4));
            accS[vt] = MFMA_BF16(af, bf, accS[vt], 0, 0, 0);
        }
    }
    __syncthreads();

    #pragma unroll
    for (int r = 0; r < 4; ++r) {
        const int ww = (wid << 4) + (q << 2) + r;
        float m = -3.0e38f;
        #pragma unroll
        for (int vt = 0; vt < 8; ++vt) m = fmaxf(m, accS[vt][r]);
        m = fmaxf(m, __shfl_xor(m, 1)); m = fmaxf(m, __shfl_xor(m, 2));
        m = fmaxf(m, __shfl_xor(m, 4)); m = fmaxf(m, __shfl_xor(m, 8));
        float s = 0.f;
        #pragma unroll
        for (int vt = 0; vt < 8; ++vt) {
            const float e = __expf(accS[vt][r] - m);
            s += e;
            const int v = (vt << 4) + l15;
            *(u16*)(ldsP + ww*256 + (((v >> 3) ^ (ww & 7)) << 4) + (v & 7)*2)
                = f2b(e);
        }
        s += __shfl_xor(s, 1); s += __shfl_xor(s, 2);
        s += __shfl_xor(s, 4); s += __shfl_xor(s, 8);
        if (l15 == 0) { sMw[ww] = m; sSw[ww] = s; }
    }
    __syncthreads();

    f32x4 accO[12];
    #pragma unroll
    for (int i = 0; i < 12; ++i) accO[i] = (f32x4){0.f,0.f,0.f,0.f};
    const int prow = (wid << 4) + l15;
    #pragma unroll
    for (int ks = 0; ks < 4; ++ks) {
        const int ch = ks*4 + q;
        s16x8 bfp = *(const s16x8*)(ldsP + prow*256 + ((ch ^ (prow & 7)) << 4));
        #pragma unroll
        for (int ct = 0; ct < 12; ++ct) {
            const int vr = (ct << 4) + l15;
            s16x8 afv = *(const s16x8*)(ldsV + vr*256 + ((ch ^ (vr & 7)) << 4));
            accO[ct] = MFMA_BF16(afv, bfp, accO[ct], 0, 0, 0);
        }
    }

    const int ww = (wid << 4) + l15;
    const float mh = sMh[ww], shv = sSh[ww];
    const float mw = sMw[ww], swv = sSw[ww];
    const float M  = fmaxf(mh, mw);
    const float S  = shv*__expf(mh - M) + swv*__expf(mw - M);
    const float scw = __expf(mw - M) / S;
    const float sch = __expf(mh - M) / S;
    const size_t gb = (size_t)b*C_*HW_ + h*W_ + ww;
    #pragma unroll
    for (int ct = 0; ct < 12; ++ct) {
        #pragma unroll
        for (int r = 0; r < 4; ++r) {
            const int c = (ct << 4) + (q << 2) + r;
            const float o2 = b2f(*(const u16*)(ldsO2 + ww*400 + c*2));
            const size_t ga = gb + (size_t)c*HW_;
            out[ga] = gam*(accO[ct][r]*scw + o2*sch) + x[ga];
        }
    }
}

extern "C" void kernel_launch(void* const* d_in, const int* in_sizes, int n_in,
                              void* d_out, int out_size, void* d_ws, size_t ws_size,
                              hipStream_t stream)
{
    const float* x  = (const float*)d_in[0];
    const float* Wq = (const float*)d_in[1];
    const float* bq = (const float*)d_in[2];
    const float* Wk = (const float*)d_in[3];
    const float* bk = (const float*)d_in[4];
    const float* Wv = (const float*)d_in[5];
    const float* bv = (const float*)d_in[6];
    const float* gm = (const float*)d_in[7];
    float* out = (float*)d_out;

    u16* Qc = (u16*)d_ws;
    u16* Kc = Qc + 8388608;
    u16* Vn = Kc + 8388608;
    u16* Vc = Vn + 25165824;
    u16* O2 = Vc + 25165824;
    float* Mh = (float*)(O2 + 25165824);
    float* Sh = Mh + 131072;
    u16*  Wb = (u16*)(Sh + 131072);          // 61440 u16 (3 phases x 320 x 64)
    float* Bb = (float*)(Wb + 61440);        // 320 f32

    hipLaunchKernelGGL(kwcast, dim3(320), dim3(256), 0, stream,
                       Wq, bq, Wk, bk, Wv, bv, Wb, Bb);
    hipLaunchKernelGGL(kprojM, dim3(H_, B_), dim3(256), 0, stream,
                       x, Wb, Bb, Qc, Kc, Vn);
    hipLaunchKernelGGL(ktrv, dim3(C_, B_), dim3(256), 0, stream, Vn, Vc);
    hipLaunchKernelGGL(kC, dim3(W_, B_), dim3(512), 81920, stream,
                       Qc, Kc, Vc, O2, Mh, Sh);
    hipLaunchKernelGGL(kR, dim3(H_, B_), dim3(512), 135168, stream,
                       Qc, Kc, Vn, O2, Mh, Sh, x, gm, out);
}

// Round 4
// 204.053 us; speedup vs baseline: 6.7801x; 1.1968x over previous
//
#include <hip/hip_runtime.h>
#include <math.h>

// RCC criss-cross attention, MFMA-bf16 pipeline. B=8, C=192, CQK=64, H=W=128.
//
//  kwcast : Wq|Wk|Wv fp32 -> Wb bf16 pre-swizzled per-phase LDS image; bias
//  kxt    : x fp32 -> xT bf16, pre-swizzled per-(b,h,phase) LDS image
//  kprojM : pipelined gll GEMM -> Qc,Kc [b][w][h][c], Vn [b][c][h][w]
//           (A dbuf + counted vmcnt + raw barriers + setprio; V via LDS epilogue)
//  ktrv   : V transpose -> Vc [b][c][w][h]
//  kC     : per (b,w): e_h MFMA (diag) -> Mh,Sh; P -> PV MFMA -> O2 [b][w][h][c]
//  kR     : per (b,h): e_w MFMA -> local stats; swapped PV; merge; final out
//
// xT aliases O2's ws region (xT dead before kC writes O2).

#define B_   8
#define C_   192
#define CQK_ 64
#define H_   128
#define W_   128
#define HW_  (H_*W_)

typedef unsigned short u16;
typedef __attribute__((ext_vector_type(8))) short    s16x8;
typedef __attribute__((ext_vector_type(4))) float    f32x4;
typedef __attribute__((ext_vector_type(2))) unsigned u32x2;
#define MFMA_BF16 __builtin_amdgcn_mfma_f32_16x16x32_bf16

__device__ __forceinline__ u16 f2b(float f) {
    unsigned u = __float_as_uint(f);
    return (u16)((u + 0x7fffu + ((u >> 16) & 1u)) >> 16);   // RNE
}
__device__ __forceinline__ float b2f(u16 v) {
    return __uint_as_float(((unsigned)v) << 16);
}
// raw global->LDS 16B/lane: LDS dest = m0 + lane*16 (wave-uniform m0)
__device__ __forceinline__ void gll16(const u16* gsrc, unsigned lds_byte) {
    asm volatile("s_mov_b32 m0, %1\n\t"
                 "global_load_lds_dwordx4 %0, off"
                 :: "v"(gsrc), "s"(lds_byte) : "memory");
}

// ------------------------------------------------ W -> bf16 pre-swizzled + bias
__global__ __launch_bounds__(256) void kwcast(
    const float* __restrict__ Wq, const float* __restrict__ bq,
    const float* __restrict__ Wk, const float* __restrict__ bk,
    const float* __restrict__ Wv, const float* __restrict__ bv,
    u16* __restrict__ Wb, float* __restrict__ Bb)
{
    const int o = blockIdx.x;                // 320 rows
    const float *row, *bias; int oo;
    if (o < 64)        { row = Wq; bias = bq; oo = o;       }
    else if (o < 128)  { row = Wk; bias = bk; oo = o - 64;  }
    else               { row = Wv; bias = bv; oo = o - 128; }
    const int t = threadIdx.x;
    if (t < C_) {
        const int p = t >> 6, cc = t & 63;
        Wb[p*20480 + o*64 + (((cc >> 3) ^ (o & 7)) << 3) + (cc & 7)]
            = f2b(row[oo*C_ + t]);
    }
    if (t == C_) Bb[o] = bias[oo];
}

// ------------------- x fp32 -> xT bf16 LDS-image [b][h][p][w][chunk^(w&7)][8]
__global__ __launch_bounds__(256) void kxt(
    const float* __restrict__ x, u16* __restrict__ xT)
{
    __shared__ u16 T[24576];                 // 48 KB: [c][16 swz chunks][8]
    const int h = blockIdx.x, b = blockIdx.y;
    const float* xb = x + (size_t)b*C_*HW_ + h*W_;
    const int t = threadIdx.x;
    #pragma unroll
    for (int i = 0; i < 24; ++i) {           // stage + cast
        const int ridx = i*256 + t;
        const int c = ridx >> 5, wq = (ridx & 31) << 2;
        const f32x4 v = *(const f32x4*)(const void*)(xb + (size_t)c*HW_ + wq);
        u32x2 pk;
        pk.x = (unsigned)f2b(v[0]) | ((unsigned)f2b(v[1]) << 16);
        pk.y = (unsigned)f2b(v[2]) | ((unsigned)f2b(v[3]) << 16);
        *(u32x2*)(void*)&T[c*128 + (((wq >> 3) ^ ((c >> 3) & 15)) << 3) + (wq & 7)] = pk;
    }
    __syncthreads();
    u16* dst = xT + (size_t)(b*H_ + h)*24576;
    #pragma unroll
    for (int i = 0; i < 12; ++i) {           // emit transposed image
        const int oidx = i*256 + t;
        const int p = oidx >> 10, w = (oidx >> 3) & 127, cp = oidx & 7;
        s16x8 pk;
        #pragma unroll
        for (int e = 0; e < 8; ++e) {
            const int c = p*64 + ((cp ^ (w & 7)) << 3) + e;
            pk[e] = (short)T[c*128 + ((((w >> 3)) ^ ((c >> 3) & 15)) << 3) + (w & 7)];
        }
        *(s16x8*)(void*)(dst + p*8192 + w*64 + cp*8) = pk;
    }
}

// ---------------------------------------------------- MFMA projection GEMM
// Per (h,b): 128 w-rows x 320 o-cols, K=192 in 3 phases of 64.
// LDS (u16 idx): bufA0 [0,8192) bufA1 [8192,16384) ldsW [16384,36864)
// epilogue ldsV [8192,32768) (bufA1+W head; phase2 reads only bufA0+W tail done)
__global__ __launch_bounds__(256, 2) void kprojM(
    const u16* __restrict__ xT,
    const u16* __restrict__ Wb, const float* __restrict__ Bb,
    u16* __restrict__ Qc, u16* __restrict__ Kc, u16* __restrict__ Vn)
{
    __shared__ u16 lds[36864];               // 72 KB
    u16* ldsW = lds + 16384;
    u16* ldsV = lds + 8192;
    const int h = blockIdx.x, b = blockIdx.y;
    const int t = threadIdx.x, lane = t & 63, wid = t >> 6;
    const int l15 = lane & 15, q = lane >> 4;

    f32x4 acc[8][5];                         // bias init (drained before glls)
    #pragma unroll
    for (int ct = 0; ct < 5; ++ct) {
        const float bv = Bb[(ct*4 + wid)*16 + l15];
        #pragma unroll
        for (int r = 0; r < 8; ++r) acc[r][ct] = (f32x4){bv, bv, bv, bv};
    }

    const u16* xTb = xT + (size_t)(b*H_ + h)*24576;
    const unsigned wofs = __builtin_amdgcn_readfirstlane(32768u + (unsigned)wid*1024u);
    const unsigned aofs = __builtin_amdgcn_readfirstlane((unsigned)wid*1024u);

#define STAGE_W(p) do {                                                   \
    const u16* g = Wb + (p)*20480 + wid*512 + lane*8;                     \
    _Pragma("unroll")                                                     \
    for (int i = 0; i < 10; ++i) gll16(g + i*2048, wofs + i*4096); } while(0)
#define STAGE_A(p, ab) do {                                               \
    const u16* g = xTb + (p)*8192 + wid*512 + lane*8;                     \
    _Pragma("unroll")                                                     \
    for (int i = 0; i < 4; ++i)                                           \
        gll16(g + i*2048, aofs + (ab)*16384u + i*4096); } while(0)
#define MFMA_PHASE(ab) do {                                               \
    const u16* bA = lds + (ab)*8192;                                      \
    __builtin_amdgcn_s_setprio(1);                                        \
    _Pragma("unroll")                                                     \
    for (int ks = 0; ks < 2; ++ks) {                                      \
        s16x8 bf[5];                                                      \
        _Pragma("unroll")                                                 \
        for (int ct = 0; ct < 5; ++ct) {                                  \
            const int o = (ct*4 + wid)*16 + l15;                          \
            bf[ct] = *(const s16x8*)(const void*)                         \
                     &ldsW[o*64 + (((ks*4 + q) ^ (o & 7)) << 3)];         \
        }                                                                 \
        _Pragma("unroll")                                                 \
        for (int r = 0; r < 8; ++r) {                                     \
            const int w = r*16 + l15;                                     \
            const s16x8 af = *(const s16x8*)(const void*)                 \
                     &bA[w*64 + (((ks*4 + q) ^ (w & 7)) << 3)];           \
            _Pragma("unroll")                                             \
            for (int ct = 0; ct < 5; ++ct)                                \
                acc[r][ct] = MFMA_BF16(af, bf[ct], acc[r][ct], 0, 0, 0);  \
        }                                                                 \
    }                                                                     \
    __builtin_amdgcn_s_setprio(0); } while(0)

    STAGE_W(0); STAGE_A(0, 0); STAGE_A(1, 1);            // 18 in flight
    asm volatile("s_waitcnt vmcnt(4)" ::: "memory");     // W0+A0 landed
    __builtin_amdgcn_s_barrier();
    MFMA_PHASE(0);
    asm volatile("s_waitcnt lgkmcnt(0)" ::: "memory");
    __builtin_amdgcn_s_barrier();
    STAGE_W(1); STAGE_A(2, 0);                           // A1 + 14 in flight
    asm volatile("s_waitcnt vmcnt(4)" ::: "memory");     // A1+W1 landed
    __builtin_amdgcn_s_barrier();
    MFMA_PHASE(1);
    asm volatile("s_waitcnt lgkmcnt(0)" ::: "memory");
    __builtin_amdgcn_s_barrier();
    STAGE_W(2);
    asm volatile("s_waitcnt vmcnt(0)" ::: "memory");
    __builtin_amdgcn_s_barrier();
    MFMA_PHASE(0);
    asm volatile("s_waitcnt lgkmcnt(0)" ::: "memory");
    __builtin_amdgcn_s_barrier();

    // ---- epilogue: Q/K direct (32B segments), V via LDS transpose
    {
        const int oc = wid*16 + l15;
        #pragma unroll
        for (int r = 0; r < 8; ++r)
            #pragma unroll
            for (int rg = 0; rg < 4; ++rg) {
                const int w = r*16 + q*4 + rg;
                const size_t base = ((size_t)(b*W_ + w)*H_ + h)*CQK_ + oc;
                Qc[base] = f2b(acc[r][0][rg]);
                Kc[base] = f2b(acc[r][1][rg]);
            }
    }
    #pragma unroll
    for (int ct = 2; ct < 5; ++ct) {
        const int c = (ct - 2)*64 + wid*16 + l15;
        #pragma unroll
        for (int r = 0; r < 8; ++r) {
            const int w0 = r*16 + q*4;
            u32x2 pk;
            pk.x = (unsigned)f2b(acc[r][ct][0]) | ((unsigned)f2b(acc[r][ct][1]) << 16);
            pk.y = (unsigned)f2b(acc[r][ct][2]) | ((unsigned)f2b(acc[r][ct][3]) << 16);
            *(u32x2*)(void*)&ldsV[c*128 + (((w0 >> 3) ^ (c & 7)) << 3) + (w0 & 7)] = pk;
        }
    }
    asm volatile("s_waitcnt lgkmcnt(0)" ::: "memory");
    __builtin_amdgcn_s_barrier();
    #pragma unroll
    for (int i = 0; i < 12; ++i) {
        const int idx = i*256 + t;
        const int c = idx >> 4, j = idx & 15;
        const s16x8 v = *(const s16x8*)(const void*)&ldsV[c*128 + j*8];
        *(s16x8*)(void*)&Vn[(size_t)(b*C_ + c)*HW_ + h*W_ + ((j ^ (c & 7)) << 3)] = v;
    }
#undef STAGE_W
#undef STAGE_A
#undef MFMA_PHASE
}

// ------------------------------------------- V transpose: [c][h][w]->[c][w][h]
__global__ __launch_bounds__(256) void ktrv(
    const u16* __restrict__ Vn, u16* __restrict__ Vc)
{
    __shared__ u16 T[128*128];
    const int c = blockIdx.x, b = blockIdx.y;
    const u16* src = Vn + (size_t)(b*C_ + c)*HW_;
    u16*       dst = Vc + (size_t)(b*C_ + c)*HW_;
    const int t = threadIdx.x;
    for (int idx = t; idx < 128*16; idx += 256) {
        const int hh = idx >> 4, o = idx & 15;
        s16x8 v = *(const s16x8*)(void*)(src + hh*128 + o*8);
        *(s16x8*)(void*)(T + hh*128 + ((o ^ (hh & 7)) << 3)) = v;
    }
    __syncthreads();
    const int w = t & 127, half = t >> 7;
    for (int seg = 0; seg < 8; ++seg) {
        const int h0 = half*64 + seg*8;
        s16x8 pk;
        #pragma unroll
        for (int k = 0; k < 8; ++k) {
            const int hh = h0 + k;
            const int chunk = (w >> 3) ^ (hh & 7);
            pk[k] = (short)T[hh*128 + (chunk << 3) + (w & 7)];
        }
        *(s16x8*)(void*)(dst + w*128 + h0) = pk;
    }
}

// ------------------- column attention (per b,w): O2 raw + Mh,Sh  [512 thr]
__global__ __launch_bounds__(512) void kC(
    const u16* __restrict__ Qc, const u16* __restrict__ Kc,
    const u16* __restrict__ Vc,
    u16* __restrict__ O2, float* __restrict__ Mh, float* __restrict__ Sh)
{
    extern __shared__ char smem[];
    char* ldsQ = smem;
    char* ldsK = smem + 16384;
    char* ldsP = smem;
    char* ldsV = smem + 32768;
    const int w = blockIdx.x, b = blockIdx.y;
    const int t = threadIdx.x, lane = t & 63, wid = t >> 6;
    const int l15 = lane & 15, q = lane >> 4;

    {
        const u16* qs = Qc + (size_t)(b*W_ + w)*H_*CQK_;
        const u16* ks = Kc + (size_t)(b*W_ + w)*H_*CQK_;
        for (int idx = t; idx < 1024; idx += 512) {
            const int r = idx >> 3, o = idx & 7, so = ((o ^ (r & 7)) << 4);
            *(s16x8*)(ldsQ + r*128 + so) = *(const s16x8*)(void*)(qs + idx*8);
            *(s16x8*)(ldsK + r*128 + so) = *(const s16x8*)(void*)(ks + idx*8);
        }
        for (int idx = t; idx < 3072; idx += 512) {
            const int c = idx >> 4, o = idx & 15;
            s16x8 v = *(const s16x8*)(void*)
                      (Vc + ((size_t)(b*C_ + c)*W_ + w)*H_ + o*8);
            *(s16x8*)(ldsV + c*256 + ((o ^ (c & 7)) << 4)) = v;
        }
    }
    __syncthreads();

    f32x4 accS[8];
    #pragma unroll
    for (int i = 0; i < 8; ++i) accS[i] = (f32x4){0.f,0.f,0.f,0.f};
    const int arow = (wid << 4) + l15;
    #pragma unroll
    for (int ks = 0; ks < 2; ++ks) {
        const int ch = ks*4 + q;
        s16x8 af = *(const s16x8*)(ldsQ + arow*128 + ((ch ^ (arow & 7)) << 4));
        #pragma unroll
        for (int gt = 0; gt < 8; ++gt) {
            const int br = (gt << 4) + l15;
            s16x8 bf = *(const s16x8*)(ldsK + br*128 + ((ch ^ (br & 7)) << 4));
            accS[gt] = MFMA_BF16(af, bf, accS[gt], 0, 0, 0);
        }
    }
    __syncthreads();

    #pragma unroll
    for (int r = 0; r < 4; ++r) {
        const int hh = (wid << 4) + (q << 2) + r;
        #pragma unroll
        for (int gt = 0; gt < 8; ++gt)
            if ((gt << 4) + l15 == hh) accS[gt][r] = -3.0e38f;
        float m = -3.0e38f;
        #pragma unroll
        for (int gt = 0; gt < 8; ++gt) m = fmaxf(m, accS[gt][r]);
        m = fmaxf(m, __shfl_xor(m, 1)); m = fmaxf(m, __shfl_xor(m, 2));
        m = fmaxf(m, __shfl_xor(m, 4)); m = fmaxf(m, __shfl_xor(m, 8));
        float s = 0.f;
        #pragma unroll
        for (int gt = 0; gt < 8; ++gt) {
            const float e = __expf(accS[gt][r] - m);
            s += e;
            const int g = (gt << 4) + l15;
            *(u16*)(ldsP + hh*256 + (((g >> 3) ^ (hh & 7)) << 4) + (g & 7)*2)
                = f2b(e);
        }
        s += __shfl_xor(s, 1); s += __shfl_xor(s, 2);
        s += __shfl_xor(s, 4); s += __shfl_xor(s, 8);
        if (l15 == 0) {
            Mh[(b*W_ + w)*H_ + hh] = m;
            Sh[(b*W_ + w)*H_ + hh] = s;
        }
    }
    __syncthreads();

    f32x4 accO[12];
    #pragma unroll
    for (int i = 0; i < 12; ++i) accO[i] = (f32x4){0.f,0.f,0.f,0.f};
    #pragma unroll
    for (int ks = 0; ks < 4; ++ks) {
        const int ch = ks*4 + q;
        const int pr = (wid << 4) + l15;
        s16x8 af = *(const s16x8*)(ldsP + pr*256 + ((ch ^ (pr & 7)) << 4));
        #pragma unroll
        for (int ct = 0; ct < 12; ++ct) {
            const int vr = (ct << 4) + l15;
            s16x8 bf = *(const s16x8*)(ldsV + vr*256 + ((ch ^ (vr & 7)) << 4));
            accO[ct] = MFMA_BF16(af, bf, accO[ct], 0, 0, 0);
        }
    }
    #pragma unroll
    for (int ct = 0; ct < 12; ++ct) {
        const int c = (ct << 4) + l15;
        #pragma unroll
        for (int r = 0; r < 4; ++r) {
            const int hh = (wid << 4) + (q << 2) + r;
            O2[((size_t)(b*W_ + w)*H_ + hh)*C_ + c] = f2b(accO[ct][r]);
        }
    }
}

// -------- row attention + fused final (per b,h)  [512 thr, 132KB LDS]
__global__ __launch_bounds__(512) void kR(
    const u16* __restrict__ Qc, const u16* __restrict__ Kc,
    const u16* __restrict__ Vn, const u16* __restrict__ O2,
    const float* __restrict__ Mh, const float* __restrict__ Sh,
    const float* __restrict__ x, const float* __restrict__ gamma,
    float* __restrict__ out)
{
    extern __shared__ char smem[];
    char*  ldsQ  = smem;
    char*  ldsK  = smem + 16384;
    char*  ldsP  = smem;
    char*  ldsV  = smem + 32768;
    char*  ldsO2 = smem + 81920;
    float* sMh = (float*)(smem + 133120);
    float* sSh = sMh + 128;
    float* sMw = sSh + 128;
    float* sSw = sMw + 128;
    const int h = blockIdx.x, b = blockIdx.y;
    const int t = threadIdx.x, lane = t & 63, wid = t >> 6;
    const int l15 = lane & 15, q = lane >> 4;
    const float gam = gamma[0];

    for (int idx = t; idx < 1024; idx += 512) {
        const int r = idx >> 3, o = idx & 7, so = ((o ^ (r & 7)) << 4);
        const size_t g = ((size_t)(b*W_ + r)*H_ + h)*CQK_ + o*8;
        *(s16x8*)(ldsQ + r*128 + so) = *(const s16x8*)(void*)(Qc + g);
        *(s16x8*)(ldsK + r*128 + so) = *(const s16x8*)(void*)(Kc + g);
    }
    for (int idx = t; idx < 3072; idx += 512) {
        const int c = idx >> 4, o = idx & 15;
        s16x8 v = *(const s16x8*)(void*)
                  (Vn + (size_t)(b*C_ + c)*HW_ + h*W_ + o*8);
        *(s16x8*)(ldsV + c*256 + ((o ^ (c & 7)) << 4)) = v;
    }
    for (int idx = t; idx < 3200; idx += 512) {
        const int r = idx / 25, o = idx - r*25;
        if (o < 24) {
            s16x8 v = *(const s16x8*)(void*)
                      (O2 + ((size_t)(b*W_ + r)*H_ + h)*C_ + o*8);
            *(s16x8*)(ldsO2 + r*400 + o*16) = v;
        }
    }
    if (t < 128) {
        sMh[t] = Mh[(b*W_ + t)*H_ + h];
        sSh[t] = Sh[(b*W_ + t)*H_ + h];
    }
    __syncthreads();

    f32x4 accS[8];
    #pragma unroll
    for (int i = 0; i < 8; ++i) accS[i] = (f32x4){0.f,0.f,0.f,0.f};
    const int arow = (wid << 4) + l15;
    #pragma unroll
    for (int ks = 0; ks < 2; ++ks) {
        const int ch = ks*4 + q;
        s16x8 af = *(const s16x8*)(ldsQ + arow*128 + ((ch ^ (arow & 7)) << 4));
        #pragma unroll
        for (int vt = 0; vt < 8; ++vt) {
            const int br = (vt << 4) + l15;
            s16x8 bf = *(const s16x8*)(ldsK + br*128 + ((ch ^ (br & 7)) << 4));
            accS[vt] = MFMA_BF16(af, bf, accS[vt], 0, 0, 0);
        }
    }
    __syncthreads();

    #pragma unroll
    for (int r = 0; r < 4; ++r) {
        const int ww = (wid << 4) + (q << 2) + r;
        float m = -3.0e38f;
        #pragma unroll
        for (int vt = 0; vt < 8; ++vt) m = fmaxf(m, accS[vt][r]);
        m = fmaxf(m, __shfl_xor(m, 1)); m = fmaxf(m, __shfl_xor(m, 2));
        m = fmaxf(m, __shfl_xor(m, 4)); m = fmaxf(m, __shfl_xor(m, 8));
        float s = 0.f;
        #pragma unroll
        for (int vt = 0; vt < 8; ++vt) {
            const float e = __expf(accS[vt][r] - m);
            s += e;
            const int v = (vt << 4) + l15;
            *(u16*)(ldsP + ww*256 + (((v >> 3) ^ (ww & 7)) << 4) + (v & 7)*2)
                = f2b(e);
        }
        s += __shfl_xor(s, 1); s += __shfl_xor(s, 2);
        s += __shfl_xor(s, 4); s += __shfl_xor(s, 8);
        if (l15 == 0) { sMw[ww] = m; sSw[ww] = s; }
    }
    __syncthreads();

    f32x4 accO[12];
    #pragma unroll
    for (int i = 0; i < 12; ++i) accO[i] = (f32x4){0.f,0.f,0.f,0.f};
    const int prow = (wid << 4) + l15;
    #pragma unroll
    for (int ks = 0; ks < 4; ++ks) {
        const int ch = ks*4 + q;
        s16x8 bfp = *(const s16x8*)(ldsP + prow*256 + ((ch ^ (prow & 7)) << 4));
        #pragma unroll
        for (int ct = 0; ct < 12; ++ct) {
            const int vr = (ct << 4) + l15;
            s16x8 afv = *(const s16x8*)(ldsV + vr*256 + ((ch ^ (vr & 7)) << 4));
            accO[ct] = MFMA_BF16(afv, bfp, accO[ct], 0, 0, 0);
        }
    }

    const int ww = (wid << 4) + l15;
    const float mh = sMh[ww], shv = sSh[ww];
    const float mw = sMw[ww], swv = sSw[ww];
    const float M  = fmaxf(mh, mw);
    const float S  = shv*__expf(mh - M) + swv*__expf(mw - M);
    const float scw = __expf(mw - M) / S;
    const float sch = __expf(mh - M) / S;
    const size_t gb = (size_t)b*C_*HW_ + h*W_ + ww;
    #pragma unroll
    for (int ct = 0; ct < 12; ++ct) {
        #pragma unroll
        for (int r = 0; r < 4; ++r) {
            const int c = (ct << 4) + (q << 2) + r;
            const float o2 = b2f(*(const u16*)(ldsO2 + ww*400 + c*2));
            const size_t ga = gb + (size_t)c*HW_;
            out[ga] = gam*(accO[ct][r]*scw + o2*sch) + x[ga];
        }
    }
}

extern "C" void kernel_launch(void* const* d_in, const int* in_sizes, int n_in,
                              void* d_out, int out_size, void* d_ws, size_t ws_size,
                              hipStream_t stream)
{
    const float* x  = (const float*)d_in[0];
    const float* Wq = (const float*)d_in[1];
    const float* bq = (const float*)d_in[2];
    const float* Wk = (const float*)d_in[3];
    const float* bk = (const float*)d_in[4];
    const float* Wv = (const float*)d_in[5];
    const float* bv = (const float*)d_in[6];
    const float* gm = (const float*)d_in[7];
    float* out = (float*)d_out;

    u16* Qc = (u16*)d_ws;
    u16* Kc = Qc + 8388608;
    u16* Vn = Kc + 8388608;
    u16* Vc = Vn + 25165824;
    u16* O2 = Vc + 25165824;                 // 25165824 u16
    u16* xT = O2;                            // alias: xT dead before kC writes O2
    float* Mh = (float*)(O2 + 25165824);
    float* Sh = Mh + 131072;
    u16*  Wb = (u16*)(Sh + 131072);          // 61440 u16
    float* Bb = (float*)(Wb + 61440);        // 320 f32

    hipLaunchKernelGGL(kwcast, dim3(320), dim3(256), 0, stream,
                       Wq, bq, Wk, bk, Wv, bv, Wb, Bb);
    hipLaunchKernelGGL(kxt, dim3(H_, B_), dim3(256), 0, stream, x, xT);
    hipLaunchKernelGGL(kprojM, dim3(H_, B_), dim3(256), 0, stream,
                       xT, Wb, Bb, Qc, Kc, Vn);
    hipLaunchKernelGGL(ktrv, dim3(C_, B_), dim3(256), 0, stream, Vn, Vc);
    hipLaunchKernelGGL(kC, dim3(W_, B_), dim3(512), 81920, stream,
                       Qc, Kc, Vc, O2, Mh, Sh);
    hipLaunchKernelGGL(kR, dim3(H_, B_), dim3(512), 135168, stream,
                       Qc, Kc, Vn, O2, Mh, Sh, x, gm, out);
}